// Round 1
// baseline (3609.045 us; speedup 1.0000x reference)
//
#include <hip/hip_runtime.h>

#define NN 50000
#define NE 250000

// ---------- float max <-> monotone uint encoding for atomicMax on floats ----
__device__ __forceinline__ unsigned enc_f(float f) {
    unsigned u = __float_as_uint(f);
    return (u & 0x80000000u) ? ~u : (u | 0x80000000u);
}
__device__ __forceinline__ float dec_f(unsigned u) {
    return __uint_as_float((u & 0x80000000u) ? (u ^ 0x80000000u) : ~u);
}

// ---------------------------------------------------------------------------
// GEMM: out[M][128] = concat_k(A0[,A1]) @ W[KH*128][128], optional relu,
// optional fused score sout[r] = out[r] . wsc, optional row-scale 1/rowdiv[r]
// applied to the A0 half (for applied_n = num/den).
// Block: 256 thr = 8 rowgroups x 32 colgroups; 32 rows/block; 4x4 reg tile.
// In-place safe (out may alias A0): each row is read only by the wave that
// writes it, and all its loads precede the store in wave program order.
// ---------------------------------------------------------------------------
template<int KH, bool RELU, bool SCORE, bool DIV>
__global__ __launch_bounds__(256) void gemm_kernel(
    const float* __restrict__ A0, const float* __restrict__ A1,
    const float* __restrict__ rowdiv,
    const float* __restrict__ W, const float* __restrict__ wsc,
    float* __restrict__ out, float* __restrict__ sout, int M)
{
    const int tid = threadIdx.x;
    const int cg  = tid & 31;   // colgroup: cols cg*4 .. cg*4+3
    const int rg  = tid >> 5;   // rowgroup: 4 rows
    const int rbase = blockIdx.x * 32 + rg * 4;

    float acc[4][4] = {};
    int   rows[4];
    float scale[4];
#pragma unroll
    for (int i = 0; i < 4; ++i) {
        int r = rbase + i;
        if (r > M - 1) r = M - 1;
        rows[i]  = r;
        scale[i] = 1.0f;
    }
    if (DIV) {
#pragma unroll
        for (int i = 0; i < 4; ++i) scale[i] = 1.0f / rowdiv[rows[i]];
    }

    const float4* Wv = (const float4*)W;

#pragma unroll
    for (int h = 0; h < KH; ++h) {
        const float* A = (h == 0) ? A0 : A1;
#pragma unroll 4
        for (int k = 0; k < 128; k += 4) {
            float4 av[4];
#pragma unroll
            for (int i = 0; i < 4; ++i) {
                av[i] = *(const float4*)(A + (size_t)rows[i] * 128 + k);
                if (DIV && h == 0) {
                    av[i].x *= scale[i]; av[i].y *= scale[i];
                    av[i].z *= scale[i]; av[i].w *= scale[i];
                }
            }
#pragma unroll
            for (int kk = 0; kk < 4; ++kk) {
                float4 wv = Wv[(size_t)(h * 128 + k + kk) * 32 + cg];
#pragma unroll
                for (int i = 0; i < 4; ++i) {
                    float a = (kk == 0) ? av[i].x : (kk == 1) ? av[i].y
                            : (kk == 2) ? av[i].z : av[i].w;
                    acc[i][0] += a * wv.x; acc[i][1] += a * wv.y;
                    acc[i][2] += a * wv.z; acc[i][3] += a * wv.w;
                }
            }
        }
    }

    float4 wscv;
    if (SCORE) wscv = ((const float4*)wsc)[cg];

#pragma unroll
    for (int i = 0; i < 4; ++i) {
        int r = rbase + i;
        bool valid = (r < M);
        float4 v;
        v.x = acc[i][0]; v.y = acc[i][1]; v.z = acc[i][2]; v.w = acc[i][3];
        if (RELU) {
            v.x = fmaxf(v.x, 0.f); v.y = fmaxf(v.y, 0.f);
            v.z = fmaxf(v.z, 0.f); v.w = fmaxf(v.w, 0.f);
        }
        if (valid) *(float4*)(out + (size_t)r * 128 + cg * 4) = v;
        if (SCORE) {
            float s = acc[i][0] * wscv.x + acc[i][1] * wscv.y
                    + acc[i][2] * wscv.z + acc[i][3] * wscv.w;
#pragma unroll
            for (int msk = 16; msk >= 1; msk >>= 1) s += __shfl_xor(s, msk);
            if (cg == 0 && valid) sout[r] = s;
        }
    }
}

// ---------------------------------------------------------------------------
// Per-edge: 2-way softmax over (s_src, s_dst), applied_e = a0*F_src + a1*F_dst
// plus segment_max contribution m[dst] = max(m[dst], max(s_src, s_e)).
// 32 threads per edge (float4 chunks), 8 edges per block.
// ---------------------------------------------------------------------------
__global__ __launch_bounds__(256) void edge_apply_kernel(
    const float* __restrict__ Fn, const float* __restrict__ sn,
    const float* __restrict__ se_arr, const int* __restrict__ edges,
    float* __restrict__ applied, unsigned* __restrict__ menc)
{
    const int tid = threadIdx.x;
    const int sub = tid & 31;
    const int e   = blockIdx.x * 8 + (tid >> 5);
    if (e >= NE) return;
    const int src = edges[2 * e];
    const int dst = edges[2 * e + 1];
    const float ss = sn[src], sd = sn[dst], se = se_arr[e];
    const float mx = fmaxf(ss, sd);
    const float p0 = expf(ss - mx), p1 = expf(sd - mx);
    const float inv = 1.0f / (p0 + p1);
    const float a0 = p0 * inv, a1 = p1 * inv;
    const float4 fs = *(const float4*)(Fn + (size_t)src * 128 + sub * 4);
    const float4 fd = *(const float4*)(Fn + (size_t)dst * 128 + sub * 4);
    float4 o;
    o.x = a0 * fs.x + a1 * fd.x; o.y = a0 * fs.y + a1 * fd.y;
    o.z = a0 * fs.z + a1 * fd.z; o.w = a0 * fs.w + a1 * fd.w;
    *(float4*)(applied + (size_t)e * 128 + sub * 4) = o;
    if (sub == 0) atomicMax(menc + dst, enc_f(fmaxf(ss, se)));
}

// ---------------------------------------------------------------------------
// Per-edge scatter: e_n = exp(s_src - m[dst]), e_e = exp(s_e - m[dst]);
// num[dst] += e_n*F_src + e_e*F_e_new ; den[dst] += e_n + e_e.
// ---------------------------------------------------------------------------
__global__ __launch_bounds__(256) void edge_scatter_kernel(
    const float* __restrict__ Fn, const float* __restrict__ sn,
    const float* __restrict__ se_arr, const int* __restrict__ edges,
    const float* __restrict__ Fe_new, const unsigned* __restrict__ menc,
    float* __restrict__ num, float* __restrict__ den)
{
    const int tid = threadIdx.x;
    const int sub = tid & 31;
    const int e   = blockIdx.x * 8 + (tid >> 5);
    if (e >= NE) return;
    const int src = edges[2 * e];
    const int dst = edges[2 * e + 1];
    const float ss = sn[src], se = se_arr[e];
    const float md = dec_f(menc[dst]);
    const float en = expf(ss - md), ee = expf(se - md);
    const float4 fs = *(const float4*)(Fn + (size_t)src * 128 + sub * 4);
    const float4 fe = *(const float4*)(Fe_new + (size_t)e * 128 + sub * 4);
    float4 c;
    c.x = en * fs.x + ee * fe.x; c.y = en * fs.y + ee * fe.y;
    c.z = en * fs.z + ee * fe.z; c.w = en * fs.w + ee * fe.w;
    float* np = num + (size_t)dst * 128 + sub * 4;
    unsafeAtomicAdd(np + 0, c.x);
    unsafeAtomicAdd(np + 1, c.y);
    unsafeAtomicAdd(np + 2, c.z);
    unsafeAtomicAdd(np + 3, c.w);
    if (sub == 0) unsafeAtomicAdd(den + dst, en + ee);
}

// ---------------------------------------------------------------------------
extern "C" void kernel_launch(void* const* d_in, const int* in_sizes, int n_in,
                              void* d_out, int out_size, void* d_ws, size_t ws_size,
                              hipStream_t stream)
{
    const float* obj         = (const float*)d_in[0];
    const float* pred        = (const float*)d_in[1];
    const int*   edges       = (const int*)d_in[2];
    const float* W_node      = (const float*)d_in[3];
    const float* W_obj_score = (const float*)d_in[4];
    const float* W_edge      = (const float*)d_in[5];
    const float* W_rel_score = (const float*)d_in[6];
    const float* W_phi_node  = (const float*)d_in[7];
    const float* W_phi_edge  = (const float*)d_in[8];
    const float* W_node_out  = (const float*)d_in[9];
    const float* W_edge_out  = (const float*)d_in[10];
    float* out = (float*)d_out;

    char*  ws  = (char*)d_ws;
    size_t off = 0;
    auto alloc = [&](size_t nbytes) -> void* {
        void* p = ws + off;
        off = (off + nbytes + 255) & ~(size_t)255;
        return p;
    };
    float*    Fn_buf = (float*)alloc((size_t)NN * 128 * 4);
    float*    Fn_new = (float*)alloc((size_t)NN * 128 * 4);
    float*    s_n    = (float*)alloc((size_t)NN * 4);
    float*    Fe_buf = (float*)alloc((size_t)NE * 128 * 4);
    float*    Fe_new = (float*)alloc((size_t)NE * 128 * 4);
    float*    s_e    = (float*)alloc((size_t)NE * 4);
    unsigned* menc   = (unsigned*)alloc((size_t)NN * 4);
    float*    num    = (float*)alloc((size_t)NN * 128 * 4);
    float*    den    = (float*)alloc((size_t)NN * 4);
    (void)ws_size; (void)in_sizes; (void)n_in; (void)out_size;

    const int nodeBlocks  = (NN + 31) / 32;
    const int edgeBlocks  = (NE + 31) / 32;
    const int edgeBlocks8 = (NE + 7) / 8;

    for (int step = 0; step < 2; ++step) {
        const float* FnIn = (step == 0) ? obj  : Fn_buf;
        const float* FeIn = (step == 0) ? pred : Fe_buf;

        hipMemsetAsync(menc, 0, (size_t)NN * 4, stream);
        hipMemsetAsync(num,  0, (size_t)NN * 128 * 4, stream);
        hipMemsetAsync(den,  0, (size_t)NN * 4, stream);

        // F_n' = F_n @ W_node ; s_n = F_n' @ W_obj_score
        gemm_kernel<1, false, true, false><<<nodeBlocks, 256, 0, stream>>>(
            FnIn, nullptr, nullptr, W_node, W_obj_score, Fn_new, s_n, NN);
        // F_e_new = F_e @ W_edge ; s_e = F_e_new @ W_rel_score
        gemm_kernel<1, false, true, false><<<edgeBlocks, 256, 0, stream>>>(
            FeIn, nullptr, nullptr, W_edge, W_rel_score, Fe_new, s_e, NE);
        // applied_e (into Fe_buf) + segment_max m
        edge_apply_kernel<<<edgeBlocks8, 256, 0, stream>>>(
            Fn_new, s_n, s_e, edges, Fe_buf, menc);
        // scatter num/den (needs m complete)
        edge_scatter_kernel<<<edgeBlocks8, 256, 0, stream>>>(
            Fn_new, s_n, s_e, edges, Fe_new, menc, num, den);
        // F_e_next = relu(concat(applied_e, F_e_new) @ W_phi_edge)  (in place)
        gemm_kernel<2, true, false, false><<<edgeBlocks, 256, 0, stream>>>(
            Fe_buf, Fe_new, nullptr, W_phi_edge, nullptr, Fe_buf, nullptr, NE);
        // F_n = relu(concat(num/den, F_n') @ W_phi_node)
        gemm_kernel<2, true, false, true><<<nodeBlocks, 256, 0, stream>>>(
            num, Fn_new, den, W_phi_node, nullptr, Fn_buf, nullptr, NN);
    }

    // final projections
    gemm_kernel<1, false, false, false><<<nodeBlocks, 256, 0, stream>>>(
        Fn_buf, nullptr, nullptr, W_node_out, nullptr, out, nullptr, NN);
    gemm_kernel<1, false, false, false><<<edgeBlocks, 256, 0, stream>>>(
        Fe_buf, nullptr, nullptr, W_edge_out, nullptr, out + (size_t)NN * 128, nullptr, NE);
}

// Round 2
// 2354.876 us; speedup vs baseline: 1.5326x; 1.5326x over previous
//
#include <hip/hip_runtime.h>

#define NN 50000
#define NE 250000

typedef __bf16 bf16_8 __attribute__((ext_vector_type(8)));
typedef float  f32x4  __attribute__((ext_vector_type(4)));

// ---------- float max <-> monotone uint encoding for atomicMax on floats ----
__device__ __forceinline__ unsigned enc_f(float f) {
    unsigned u = __float_as_uint(f);
    return (u & 0x80000000u) ? ~u : (u | 0x80000000u);
}
__device__ __forceinline__ float dec_f(unsigned u) {
    return __uint_as_float((u & 0x80000000u) ? (u ^ 0x80000000u) : ~u);
}
// XOR-swizzle: 256B rows of bf16[128]; spreads the 16B column slots of
// 8-row stripes across banks (G4) — applied on BOTH ds_write and ds_read.
__device__ __forceinline__ int swz(int row, int bc) {
    return row * 256 + (bc ^ ((row & 7) << 4));
}

// ---------------------------------------------------------------------------
// Weight prep: Wt[c][K] = bf16(W[k][c]) — run once per launch, tiny.
// ---------------------------------------------------------------------------
__global__ __launch_bounds__(256) void wprep(const float* __restrict__ W,
                                             __bf16* __restrict__ Wt, int K) {
    int idx = blockIdx.x * 256 + threadIdx.x;  // over 128*K
    if (idx >= 128 * K) return;
    int c = idx / K, k = idx % K;
    Wt[idx] = (__bf16)W[(size_t)k * 128 + c];
}

// ---------------------------------------------------------------------------
// MFMA GEMM: out[M][128] = concat_h(A0[,A1])[M][KH*128] @ W, optional relu,
// fused score sout[r] = out[r].wsc, optional row-scale 1/rowdiv (A0 half).
// 256 thr = 4 waves in 2x2; wave computes 64x64 via 4x4 mfma_16x16x32_bf16.
// Whole K-half staged in LDS (A 32KB + Wt 32KB), swizzled.
// Fragment maps (m89-verified): A row=lane&15,k=(lane>>4)*8+j; B col=lane&15;
// D col=lane&15,row=(lane>>4)*4+r.
// ---------------------------------------------------------------------------
template<int KH, bool A0F32, bool DIV, bool RELU, bool SCORE, bool OUTF32>
__global__ __launch_bounds__(256, 2) void mfma_gemm(
    const void* __restrict__ A0, const void* __restrict__ A1,
    const float* __restrict__ rowdiv, const __bf16* __restrict__ Wt,
    const float* __restrict__ wsc, void* __restrict__ out,
    float* __restrict__ sout, int M)
{
    __shared__ __align__(16) char smem[65536];
    __shared__ float sred[128];
    char* As = smem;           // 128 rows x 256B (bf16 K=128)
    char* Ws = smem + 32768;   // 128 cols x 256B

    const int t = threadIdx.x;
    const int rowbase = blockIdx.x * 128;
    const int wv = t >> 6, lane = t & 63;
    const int wr = (wv >> 1) * 64, wc = (wv & 1) * 64;
    const int lr = lane & 15, kq = lane >> 4;

    if (SCORE && t < 128) sred[t] = 0.0f;

    f32x4 acc[4][4] = {};

#pragma unroll
    for (int h = 0; h < KH; ++h) {
        if (h) __syncthreads();  // drain reads before LDS overwrite
        // ---- stage A half (128 rows x 128 k, bf16, swizzled) ----
        const char* Asrc = (h == 0) ? (const char*)A0 : (const char*)A1;
        const bool srcF32 = (h == 0) && A0F32;
#pragma unroll
        for (int i = 0; i < 8; ++i) {
            int flat = (i * 256 + t) * 8;
            int row = flat >> 7, k = flat & 127;
            int grow = rowbase + row; if (grow > M - 1) grow = M - 1;
            bf16_8 v;
            if (srcF32) {
                const float* p = (const float*)Asrc + (size_t)grow * 128 + k;
                float sc = 1.0f;
                if (DIV && h == 0) sc = 1.0f / rowdiv[grow];
                float4 u0 = *(const float4*)p, u1 = *(const float4*)(p + 4);
                v[0] = (__bf16)(u0.x * sc); v[1] = (__bf16)(u0.y * sc);
                v[2] = (__bf16)(u0.z * sc); v[3] = (__bf16)(u0.w * sc);
                v[4] = (__bf16)(u1.x * sc); v[5] = (__bf16)(u1.y * sc);
                v[6] = (__bf16)(u1.z * sc); v[7] = (__bf16)(u1.w * sc);
            } else {
                v = *(const bf16_8*)((const __bf16*)Asrc + (size_t)grow * 128 + k);
            }
            *(bf16_8*)(As + swz(row, k * 2)) = v;
        }
        // ---- stage W half (global Wt[c][KH*128] bf16, coalesced) ----
#pragma unroll
        for (int i = 0; i < 8; ++i) {
            int flat = (i * 256 + t) * 8;
            int c = flat >> 7, k = flat & 127;
            bf16_8 v = *(const bf16_8*)(Wt + (size_t)c * (KH * 128) + h * 128 + k);
            *(bf16_8*)(Ws + swz(c, k * 2)) = v;
        }
        __syncthreads();
        // ---- compute ----
#pragma unroll
        for (int ks = 0; ks < 4; ++ks) {
            const int bc = ks * 64 + kq * 16;
            bf16_8 a[4], b[4];
#pragma unroll
            for (int ra = 0; ra < 4; ++ra)
                a[ra] = *(const bf16_8*)(As + swz(wr + 16 * ra + lr, bc));
#pragma unroll
            for (int cb = 0; cb < 4; ++cb)
                b[cb] = *(const bf16_8*)(Ws + swz(wc + 16 * cb + lr, bc));
#pragma unroll
            for (int ra = 0; ra < 4; ++ra)
#pragma unroll
                for (int cb = 0; cb < 4; ++cb)
                    acc[ra][cb] = __builtin_amdgcn_mfma_f32_16x16x32_bf16(
                        a[ra], b[cb], acc[ra][cb], 0, 0, 0);
        }
    }

    // ---- epilogue: store ----
#pragma unroll
    for (int ra = 0; ra < 4; ++ra)
#pragma unroll
        for (int cb = 0; cb < 4; ++cb) {
            const int col = wc + 16 * cb + lr;
#pragma unroll
            for (int r = 0; r < 4; ++r) {
                const int row = rowbase + wr + 16 * ra + kq * 4 + r;
                float v = acc[ra][cb][r];
                if (RELU) v = fmaxf(v, 0.0f);
                if (row < M) {
                    if (OUTF32) ((float*)out)[(size_t)row * 128 + col] = v;
                    else ((__bf16*)out)[(size_t)row * 128 + col] = (__bf16)v;
                }
            }
        }
    // ---- fused score: s[row] = sum_col D[row][col]*wsc[col] ----
    if (SCORE) {
        float wsv[4];
#pragma unroll
        for (int cb = 0; cb < 4; ++cb) wsv[cb] = wsc[wc + 16 * cb + lr];
#pragma unroll
        for (int ra = 0; ra < 4; ++ra)
#pragma unroll
            for (int r = 0; r < 4; ++r) {
                float part = acc[ra][0][r] * wsv[0] + acc[ra][1][r] * wsv[1]
                           + acc[ra][2][r] * wsv[2] + acc[ra][3][r] * wsv[3];
                part += __shfl_xor(part, 1); part += __shfl_xor(part, 2);
                part += __shfl_xor(part, 4); part += __shfl_xor(part, 8);
                if (lr == 0)
                    atomicAdd(&sred[wr + 16 * ra + kq * 4 + r], part);
            }
        __syncthreads();
        if (t < 128 && rowbase + t < M) sout[rowbase + t] = sred[t];
    }
}

// ---------------------------------------------------------------------------
// Per-edge: 2-way softmax + blend; segment_max contribution. 16 thr/edge.
// ---------------------------------------------------------------------------
__global__ __launch_bounds__(256) void edge_apply_kernel(
    const __bf16* __restrict__ Fn, const float* __restrict__ sn,
    const float* __restrict__ se_arr, const int* __restrict__ edges,
    __bf16* __restrict__ applied, unsigned* __restrict__ menc)
{
    const int t = threadIdx.x;
    const int sub = t & 15;
    const int e = blockIdx.x * 16 + (t >> 4);
    if (e >= NE) return;
    const int src = edges[2 * e];
    const int dst = edges[2 * e + 1];
    const float ss = sn[src], sd = sn[dst], se = se_arr[e];
    const float mx = fmaxf(ss, sd);
    const float p0 = expf(ss - mx), p1 = expf(sd - mx);
    const float inv = 1.0f / (p0 + p1);
    const float a0 = p0 * inv, a1 = p1 * inv;
    bf16_8 fs = *(const bf16_8*)(Fn + (size_t)src * 128 + sub * 8);
    bf16_8 fd = *(const bf16_8*)(Fn + (size_t)dst * 128 + sub * 8);
    bf16_8 o;
#pragma unroll
    for (int j = 0; j < 8; ++j)
        o[j] = (__bf16)(a0 * (float)fs[j] + a1 * (float)fd[j]);
    *(bf16_8*)(applied + (size_t)e * 128 + sub * 8) = o;
    if (sub == 0) atomicMax(menc + dst, enc_f(fmaxf(ss, se)));
}

// ---------------------------------------------------------------------------
// Per-edge scatter into num/den. 16 thr/edge, fp32 atomics.
// ---------------------------------------------------------------------------
__global__ __launch_bounds__(256) void edge_scatter_kernel(
    const __bf16* __restrict__ Fn, const float* __restrict__ sn,
    const float* __restrict__ se_arr, const int* __restrict__ edges,
    const __bf16* __restrict__ Fe_new, const unsigned* __restrict__ menc,
    float* __restrict__ num, float* __restrict__ den)
{
    const int t = threadIdx.x;
    const int sub = t & 15;
    const int e = blockIdx.x * 16 + (t >> 4);
    if (e >= NE) return;
    const int src = edges[2 * e];
    const int dst = edges[2 * e + 1];
    const float ss = sn[src], se = se_arr[e];
    const float md = dec_f(menc[dst]);
    const float en = expf(ss - md), ee = expf(se - md);
    bf16_8 fs = *(const bf16_8*)(Fn + (size_t)src * 128 + sub * 8);
    bf16_8 fe = *(const bf16_8*)(Fe_new + (size_t)e * 128 + sub * 8);
    float* np = num + (size_t)dst * 128 + sub * 8;
#pragma unroll
    for (int j = 0; j < 8; ++j)
        unsafeAtomicAdd(np + j, en * (float)fs[j] + ee * (float)fe[j]);
    if (sub == 0) unsafeAtomicAdd(den + dst, en + ee);
}

// ---------------------------------------------------------------------------
extern "C" void kernel_launch(void* const* d_in, const int* in_sizes, int n_in,
                              void* d_out, int out_size, void* d_ws, size_t ws_size,
                              hipStream_t stream)
{
    const float* obj         = (const float*)d_in[0];
    const float* pred        = (const float*)d_in[1];
    const int*   edges       = (const int*)d_in[2];
    const float* W_node      = (const float*)d_in[3];
    const float* W_obj_score = (const float*)d_in[4];
    const float* W_edge      = (const float*)d_in[5];
    const float* W_rel_score = (const float*)d_in[6];
    const float* W_phi_node  = (const float*)d_in[7];
    const float* W_phi_edge  = (const float*)d_in[8];
    const float* W_node_out  = (const float*)d_in[9];
    const float* W_edge_out  = (const float*)d_in[10];
    float* out = (float*)d_out;

    char*  ws  = (char*)d_ws;
    size_t off = 0;
    auto alloc = [&](size_t nbytes) -> void* {
        void* p = ws + off;
        off = (off + nbytes + 255) & ~(size_t)255;
        return p;
    };
    __bf16*   FnA  = (__bf16*)alloc((size_t)NN * 128 * 2);   // F_n state
    __bf16*   FnN  = (__bf16*)alloc((size_t)NN * 128 * 2);   // F_n @ W_node
    float*    s_n  = (float*)alloc((size_t)NN * 4);
    __bf16*   FeA  = (__bf16*)alloc((size_t)NE * 128 * 2);   // applied_e / F_e state
    __bf16*   FeN  = (__bf16*)alloc((size_t)NE * 128 * 2);   // F_e @ W_edge
    float*    s_e  = (float*)alloc((size_t)NE * 4);
    unsigned* menc = (unsigned*)alloc((size_t)NN * 4);
    float*    num  = (float*)alloc((size_t)NN * 128 * 4);
    float*    den  = (float*)alloc((size_t)NN * 4);
    __bf16*   Wn_t  = (__bf16*)alloc((size_t)128 * 128 * 2);
    __bf16*   We_t  = (__bf16*)alloc((size_t)128 * 128 * 2);
    __bf16*   Wpn_t = (__bf16*)alloc((size_t)128 * 256 * 2);
    __bf16*   Wpe_t = (__bf16*)alloc((size_t)128 * 256 * 2);
    __bf16*   Wno_t = (__bf16*)alloc((size_t)128 * 128 * 2);
    __bf16*   Weo_t = (__bf16*)alloc((size_t)128 * 128 * 2);
    (void)ws_size; (void)in_sizes; (void)n_in; (void)out_size;

    // weight prep (tiny)
    wprep<<<64, 256, 0, stream>>>(W_node, Wn_t, 128);
    wprep<<<64, 256, 0, stream>>>(W_edge, We_t, 128);
    wprep<<<128, 256, 0, stream>>>(W_phi_node, Wpn_t, 256);
    wprep<<<128, 256, 0, stream>>>(W_phi_edge, Wpe_t, 256);
    wprep<<<64, 256, 0, stream>>>(W_node_out, Wno_t, 128);
    wprep<<<64, 256, 0, stream>>>(W_edge_out, Weo_t, 128);

    const int nodeBlocks = (NN + 127) / 128;   // 391
    const int edgeBlocks = (NE + 127) / 128;   // 1954
    const int eBlocks16  = (NE + 15) / 16;     // 15625

    for (int step = 0; step < 2; ++step) {
        hipMemsetAsync(menc, 0, (size_t)NN * 4, stream);
        hipMemsetAsync(num,  0, (size_t)NN * 128 * 4, stream);
        hipMemsetAsync(den,  0, (size_t)NN * 4, stream);

        // F_n' = F_n @ W_node ; s_n
        if (step == 0)
            mfma_gemm<1, true, false, false, true, false><<<nodeBlocks, 256, 0, stream>>>(
                obj, nullptr, nullptr, Wn_t, W_obj_score, FnN, s_n, NN);
        else
            mfma_gemm<1, false, false, false, true, false><<<nodeBlocks, 256, 0, stream>>>(
                FnA, nullptr, nullptr, Wn_t, W_obj_score, FnN, s_n, NN);
        // F_e_new = F_e @ W_edge ; s_e
        if (step == 0)
            mfma_gemm<1, true, false, false, true, false><<<edgeBlocks, 256, 0, stream>>>(
                pred, nullptr, nullptr, We_t, W_rel_score, FeN, s_e, NE);
        else
            mfma_gemm<1, false, false, false, true, false><<<edgeBlocks, 256, 0, stream>>>(
                FeA, nullptr, nullptr, We_t, W_rel_score, FeN, s_e, NE);
        // applied_e (-> FeA) + segment_max
        edge_apply_kernel<<<eBlocks16, 256, 0, stream>>>(FnN, s_n, s_e, edges, FeA, menc);
        // scatter num/den
        edge_scatter_kernel<<<eBlocks16, 256, 0, stream>>>(FnN, s_n, s_e, edges, FeN, menc, num, den);
        // F_e = relu(concat(applied_e, F_e_new) @ W_phi_edge)  (in place on FeA)
        mfma_gemm<2, false, false, true, false, false><<<edgeBlocks, 256, 0, stream>>>(
            FeA, FeN, nullptr, Wpe_t, nullptr, FeA, nullptr, NE);
        // F_n = relu(concat(num/den, F_n') @ W_phi_node)
        mfma_gemm<2, true, true, true, false, false><<<nodeBlocks, 256, 0, stream>>>(
            num, FnN, den, Wpn_t, nullptr, FnA, nullptr, NN);
    }

    // final projections (fp32 out)
    mfma_gemm<1, false, false, false, false, true><<<nodeBlocks, 256, 0, stream>>>(
        FnA, nullptr, nullptr, Wno_t, nullptr, out, nullptr, NN);
    mfma_gemm<1, false, false, false, false, true><<<edgeBlocks, 256, 0, stream>>>(
        FeA, nullptr, nullptr, Weo_t, nullptr, out + (size_t)NN * 128, nullptr, NE);
}

// Round 5
// 762.363 us; speedup vs baseline: 4.7340x; 3.0889x over previous
//
#include <hip/hip_runtime.h>

#define NN 50000
#define NE 250000

typedef __bf16 bf16_8 __attribute__((ext_vector_type(8)));
typedef __bf16 bf16_2 __attribute__((ext_vector_type(2)));
typedef float  f32x4  __attribute__((ext_vector_type(4)));

// XOR-swizzle: 256B rows of bf16[128]; spreads the 16B column slots of
// 8-row stripes across banks (G4) — applied on BOTH ds_write and ds_read.
__device__ __forceinline__ int swz(int row, int bc) {
    return row * 256 + (bc ^ ((row & 7) << 4));
}

// ---------------------------------------------------------------------------
// Weight prep: Wt[c][K] = bf16(W[k][c]) — run once per launch, tiny.
// ---------------------------------------------------------------------------
__global__ __launch_bounds__(256) void wprep(const float* __restrict__ W,
                                             __bf16* __restrict__ Wt, int K) {
    int idx = blockIdx.x * 256 + threadIdx.x;  // over 128*K
    if (idx >= 128 * K) return;
    int c = idx / K, k = idx % K;
    Wt[idx] = (__bf16)W[(size_t)k * 128 + c];
}

// ---------------------------------------------------------------------------
// CSR build (edges are constant across steps -> once per launch).
// ---------------------------------------------------------------------------
__global__ __launch_bounds__(256) void csr_count(const int* __restrict__ edges,
                                                 unsigned* __restrict__ counts) {
    int e = blockIdx.x * 256 + threadIdx.x;
    if (e < NE) atomicAdd(&counts[edges[2 * e + 1]], 1u);
}

// single-block chunked exclusive scan of counts[NN] -> offs[NN+1]
__global__ __launch_bounds__(256) void csr_scan(const unsigned* __restrict__ counts,
                                                unsigned* __restrict__ offs) {
    __shared__ unsigned partial[257];
    const int t = threadIdx.x;
    const int chunk = (NN + 255) / 256;
    const int lo = t * chunk;
    const int hi = (lo + chunk < NN) ? lo + chunk : NN;
    unsigned s = 0;
    for (int i = lo; i < hi; ++i) s += counts[i];
    partial[t + 1] = s;
    if (t == 0) partial[0] = 0;
    __syncthreads();
    if (t == 0)
        for (int i = 1; i <= 256; ++i) partial[i] += partial[i - 1];
    __syncthreads();
    unsigned run = partial[t];
    for (int i = lo; i < hi; ++i) { offs[i] = run; run += counts[i]; }
    if (t == 255) offs[NN] = run;
}

__global__ __launch_bounds__(256) void csr_fill(const int* __restrict__ edges,
                                                unsigned* __restrict__ cursor,
                                                int* __restrict__ csr) {
    int e = blockIdx.x * 256 + threadIdx.x;
    if (e >= NE) return;
    int d = edges[2 * e + 1];
    unsigned p = atomicAdd(&cursor[d], 1u);
    csr[p] = e;
}

// ---------------------------------------------------------------------------
// MFMA GEMM: out[M][128] = concat_h(A0[,A1])[M][KH*128] @ W, optional relu,
// fused score sout[r] = out[r].wsc. 256 thr = 4 waves in 2x2; each wave
// 64x64 via 4x4 mfma_16x16x32_bf16. K-half staged in LDS, swizzled.
// Fragment maps (m89): A row=lane&15,k=(lane>>4)*8+j; B col=lane&15;
// D col=lane&15,row=(lane>>4)*4+r.
// ---------------------------------------------------------------------------
template<int KH, bool A0F32, bool RELU, bool SCORE, bool OUTF32>
__global__ __launch_bounds__(256, 2) void mfma_gemm(
    const void* __restrict__ A0, const void* __restrict__ A1,
    const __bf16* __restrict__ Wt, const float* __restrict__ wsc,
    void* __restrict__ out, float* __restrict__ sout, int M)
{
    __shared__ __align__(16) char smem[65536];
    __shared__ float sred[128];
    char* As = smem;           // 128 rows x 256B (bf16 K=128)
    char* Ws = smem + 32768;   // 128 cols x 256B

    const int t = threadIdx.x;
    const int rowbase = blockIdx.x * 128;
    const int wv = t >> 6, lane = t & 63;
    const int wr = (wv >> 1) * 64, wc = (wv & 1) * 64;
    const int lr = lane & 15, kq = lane >> 4;

    if (SCORE && t < 128) sred[t] = 0.0f;

    f32x4 acc[4][4] = {};

#pragma unroll
    for (int h = 0; h < KH; ++h) {
        if (h) __syncthreads();  // drain reads before LDS overwrite
        const char* Asrc = (h == 0) ? (const char*)A0 : (const char*)A1;
        const bool srcF32 = (h == 0) && A0F32;
#pragma unroll
        for (int i = 0; i < 8; ++i) {
            int flat = (i * 256 + t) * 8;
            int row = flat >> 7, k = flat & 127;
            int grow = rowbase + row; if (grow > M - 1) grow = M - 1;
            bf16_8 v;
            if (srcF32) {
                const float* p = (const float*)Asrc + (size_t)grow * 128 + k;
                float4 u0 = *(const float4*)p, u1 = *(const float4*)(p + 4);
                v[0] = (__bf16)u0.x; v[1] = (__bf16)u0.y;
                v[2] = (__bf16)u0.z; v[3] = (__bf16)u0.w;
                v[4] = (__bf16)u1.x; v[5] = (__bf16)u1.y;
                v[6] = (__bf16)u1.z; v[7] = (__bf16)u1.w;
            } else {
                v = *(const bf16_8*)((const __bf16*)Asrc + (size_t)grow * 128 + k);
            }
            *(bf16_8*)(As + swz(row, k * 2)) = v;
        }
#pragma unroll
        for (int i = 0; i < 8; ++i) {
            int flat = (i * 256 + t) * 8;
            int c = flat >> 7, k = flat & 127;
            bf16_8 v = *(const bf16_8*)(Wt + (size_t)c * (KH * 128) + h * 128 + k);
            *(bf16_8*)(Ws + swz(c, k * 2)) = v;
        }
        __syncthreads();
#pragma unroll
        for (int ks = 0; ks < 4; ++ks) {
            const int bc = ks * 64 + kq * 16;
            bf16_8 a[4], b[4];
#pragma unroll
            for (int ra = 0; ra < 4; ++ra)
                a[ra] = *(const bf16_8*)(As + swz(wr + 16 * ra + lr, bc));
#pragma unroll
            for (int cb = 0; cb < 4; ++cb)
                b[cb] = *(const bf16_8*)(Ws + swz(wc + 16 * cb + lr, bc));
#pragma unroll
            for (int ra = 0; ra < 4; ++ra)
#pragma unroll
                for (int cb = 0; cb < 4; ++cb)
                    acc[ra][cb] = __builtin_amdgcn_mfma_f32_16x16x32_bf16(
                        a[ra], b[cb], acc[ra][cb], 0, 0, 0);
        }
    }

#pragma unroll
    for (int ra = 0; ra < 4; ++ra)
#pragma unroll
        for (int cb = 0; cb < 4; ++cb) {
            const int col = wc + 16 * cb + lr;
#pragma unroll
            for (int r = 0; r < 4; ++r) {
                const int row = rowbase + wr + 16 * ra + kq * 4 + r;
                float v = acc[ra][cb][r];
                if (RELU) v = fmaxf(v, 0.0f);
                if (row < M) {
                    if (OUTF32) ((float*)out)[(size_t)row * 128 + col] = v;
                    else ((__bf16*)out)[(size_t)row * 128 + col] = (__bf16)v;
                }
            }
        }
    if (SCORE) {
        float wsv[4];
#pragma unroll
        for (int cb = 0; cb < 4; ++cb) wsv[cb] = wsc[wc + 16 * cb + lr];
#pragma unroll
        for (int ra = 0; ra < 4; ++ra)
#pragma unroll
            for (int r = 0; r < 4; ++r) {
                float part = acc[ra][0][r] * wsv[0] + acc[ra][1][r] * wsv[1]
                           + acc[ra][2][r] * wsv[2] + acc[ra][3][r] * wsv[3];
                part += __shfl_xor(part, 1); part += __shfl_xor(part, 2);
                part += __shfl_xor(part, 4); part += __shfl_xor(part, 8);
                if (lr == 0)
                    atomicAdd(&sred[wr + 16 * ra + kq * 4 + r], part);
            }
        __syncthreads();
        if (t < 128 && rowbase + t < M) sout[rowbase + t] = sred[t];
    }
}

// ---------------------------------------------------------------------------
// Per-edge: 2-way softmax + blend (applied_e). 16 thr/edge. No atomics.
// ---------------------------------------------------------------------------
__global__ __launch_bounds__(256) void edge_apply_kernel(
    const __bf16* __restrict__ Fn, const float* __restrict__ sn,
    const int* __restrict__ edges, __bf16* __restrict__ applied)
{
    const int t = threadIdx.x;
    const int sub = t & 15;
    const int e = blockIdx.x * 16 + (t >> 4);
    if (e >= NE) return;
    const int src = edges[2 * e];
    const int dst = edges[2 * e + 1];
    const float ss = sn[src], sd = sn[dst];
    const float mx = fmaxf(ss, sd);
    const float p0 = expf(ss - mx), p1 = expf(sd - mx);
    const float inv = 1.0f / (p0 + p1);
    const float a0 = p0 * inv, a1 = p1 * inv;
    bf16_8 fs = *(const bf16_8*)(Fn + (size_t)src * 128 + sub * 8);
    bf16_8 fd = *(const bf16_8*)(Fn + (size_t)dst * 128 + sub * 8);
    bf16_8 o;
#pragma unroll
    for (int j = 0; j < 8; ++j)
        o[j] = (__bf16)(a0 * (float)fs[j] + a1 * (float)fd[j]);
    *(bf16_8*)(applied + (size_t)e * 128 + sub * 8) = o;
}

// ---------------------------------------------------------------------------
// CSR aggregate: one wave per dst node. Pass 1: m = max over incident edges
// of max(s_src, s_e). Pass 2: num += e_n*F_src + e_e*F_e_new, den += e_n+e_e;
// write applied_n = num/den as bf16. Replaces all scatter atomics.
// ---------------------------------------------------------------------------
__global__ __launch_bounds__(256) void aggregate_kernel(
    const int* __restrict__ edges, const int* __restrict__ csr,
    const unsigned* __restrict__ offs, const __bf16* __restrict__ FnN,
    const float* __restrict__ s_n, const float* __restrict__ s_e,
    const __bf16* __restrict__ FeN, __bf16* __restrict__ applied_n)
{
    const int t = threadIdx.x;
    const int lane = t & 63;
    const int n = blockIdx.x * 4 + (t >> 6);
    if (n >= NN) return;
    const unsigned beg = offs[n], end = offs[n + 1];

    // pass 1: segment max
    float m = -1e30f;
    for (unsigned i = beg + lane; i < end; i += 64) {
        int e = csr[i];
        int src = edges[2 * e];
        m = fmaxf(m, fmaxf(s_n[src], s_e[e]));
    }
#pragma unroll
    for (int msk = 32; msk >= 1; msk >>= 1) m = fmaxf(m, __shfl_xor(m, msk));

    // pass 2: cooperative row gathers, register accumulation
    float a0 = 0.f, a1 = 0.f, dn = 0.f;
    for (unsigned i = beg; i < end; ++i) {
        int e = csr[i];
        int src = edges[2 * e];
        float en = expf(s_n[src] - m), ee = expf(s_e[e] - m);
        bf16_2 fs = *(const bf16_2*)(FnN + (size_t)src * 128 + lane * 2);
        bf16_2 fe = *(const bf16_2*)(FeN + (size_t)e * 128 + lane * 2);
        a0 += en * (float)fs[0] + ee * (float)fe[0];
        a1 += en * (float)fs[1] + ee * (float)fe[1];
        dn += en + ee;
    }
    const float inv = 1.0f / dn;
    bf16_2 o;
    o[0] = (__bf16)(a0 * inv);
    o[1] = (__bf16)(a1 * inv);
    *(bf16_2*)(applied_n + (size_t)n * 128 + lane * 2) = o;
}

// ---------------------------------------------------------------------------
extern "C" void kernel_launch(void* const* d_in, const int* in_sizes, int n_in,
                              void* d_out, int out_size, void* d_ws, size_t ws_size,
                              hipStream_t stream)
{
    const float* obj         = (const float*)d_in[0];
    const float* pred        = (const float*)d_in[1];
    const int*   edges       = (const int*)d_in[2];
    const float* W_node      = (const float*)d_in[3];
    const float* W_obj_score = (const float*)d_in[4];
    const float* W_edge      = (const float*)d_in[5];
    const float* W_rel_score = (const float*)d_in[6];
    const float* W_phi_node  = (const float*)d_in[7];
    const float* W_phi_edge  = (const float*)d_in[8];
    const float* W_node_out  = (const float*)d_in[9];
    const float* W_edge_out  = (const float*)d_in[10];
    float* out = (float*)d_out;

    char*  ws  = (char*)d_ws;
    size_t off = 0;
    auto alloc = [&](size_t nbytes) -> void* {
        void* p = ws + off;
        off = (off + nbytes + 255) & ~(size_t)255;
        return p;
    };
    __bf16*   FnA   = (__bf16*)alloc((size_t)NN * 128 * 2);   // F_n state
    __bf16*   FnN   = (__bf16*)alloc((size_t)NN * 128 * 2);   // F_n @ W_node
    __bf16*   FnApp = (__bf16*)alloc((size_t)NN * 128 * 2);   // applied_n
    float*    s_n   = (float*)alloc((size_t)NN * 4);
    __bf16*   FeA   = (__bf16*)alloc((size_t)NE * 128 * 2);   // applied_e / F_e state
    __bf16*   FeN   = (__bf16*)alloc((size_t)NE * 128 * 2);   // F_e @ W_edge
    float*    s_e   = (float*)alloc((size_t)NE * 4);
    unsigned* counts = (unsigned*)alloc((size_t)NN * 4);
    unsigned* offs   = (unsigned*)alloc((size_t)(NN + 1) * 4);
    unsigned* cursor = (unsigned*)alloc((size_t)NN * 4);
    int*      csr    = (int*)alloc((size_t)NE * 4);
    __bf16*   Wn_t  = (__bf16*)alloc((size_t)128 * 128 * 2);
    __bf16*   We_t  = (__bf16*)alloc((size_t)128 * 128 * 2);
    __bf16*   Wpn_t = (__bf16*)alloc((size_t)128 * 256 * 2);
    __bf16*   Wpe_t = (__bf16*)alloc((size_t)128 * 256 * 2);
    __bf16*   Wno_t = (__bf16*)alloc((size_t)128 * 128 * 2);
    __bf16*   Weo_t = (__bf16*)alloc((size_t)128 * 128 * 2);
    (void)ws_size; (void)in_sizes; (void)n_in; (void)out_size;

    // weight prep (tiny)
    wprep<<<64, 256, 0, stream>>>(W_node, Wn_t, 128);
    wprep<<<64, 256, 0, stream>>>(W_edge, We_t, 128);
    wprep<<<128, 256, 0, stream>>>(W_phi_node, Wpn_t, 256);
    wprep<<<128, 256, 0, stream>>>(W_phi_edge, Wpe_t, 256);
    wprep<<<64, 256, 0, stream>>>(W_node_out, Wno_t, 128);
    wprep<<<64, 256, 0, stream>>>(W_edge_out, Weo_t, 128);

    // CSR build (once per launch; edges constant across steps)
    const int eB = (NE + 255) / 256;
    hipMemsetAsync(counts, 0, (size_t)NN * 4, stream);
    csr_count<<<eB, 256, 0, stream>>>(edges, counts);
    csr_scan<<<1, 256, 0, stream>>>(counts, offs);
    hipMemcpyAsync(cursor, offs, (size_t)NN * 4, hipMemcpyDeviceToDevice, stream);
    csr_fill<<<eB, 256, 0, stream>>>(edges, cursor, csr);

    const int nodeBlocks = (NN + 127) / 128;   // 391
    const int edgeBlocks = (NE + 127) / 128;   // 1954
    const int eBlocks16  = (NE + 15) / 16;     // 15625
    const int aggBlocks  = (NN + 3) / 4;       // 12500

    for (int step = 0; step < 2; ++step) {
        // F_n' = F_n @ W_node ; s_n
        if (step == 0)
            mfma_gemm<1, true, false, true, false><<<nodeBlocks, 256, 0, stream>>>(
                obj, nullptr, Wn_t, W_obj_score, FnN, s_n, NN);
        else
            mfma_gemm<1, false, false, true, false><<<nodeBlocks, 256, 0, stream>>>(
                FnA, nullptr, Wn_t, W_obj_score, FnN, s_n, NN);
        // F_e_new = F_e @ W_edge ; s_e
        if (step == 0)
            mfma_gemm<1, true, false, true, false><<<edgeBlocks, 256, 0, stream>>>(
                pred, nullptr, We_t, W_rel_score, FeN, s_e, NE);
        else
            mfma_gemm<1, false, false, true, false><<<edgeBlocks, 256, 0, stream>>>(
                FeA, nullptr, We_t, W_rel_score, FeN, s_e, NE);
        // applied_e (-> FeA)
        edge_apply_kernel<<<eBlocks16, 256, 0, stream>>>(FnN, s_n, edges, FeA);
        // CSR aggregate -> applied_n (bf16)
        aggregate_kernel<<<aggBlocks, 256, 0, stream>>>(
            edges, csr, offs, FnN, s_n, s_e, FeN, FnApp);
        // F_e = relu(concat(applied_e, F_e_new) @ W_phi_edge)  (in place on FeA)
        mfma_gemm<2, false, true, false, false><<<edgeBlocks, 256, 0, stream>>>(
            FeA, FeN, Wpe_t, nullptr, FeA, nullptr, NE);
        // F_n = relu(concat(applied_n, F_n') @ W_phi_node)
        mfma_gemm<2, false, true, false, false><<<nodeBlocks, 256, 0, stream>>>(
            FnApp, FnN, Wpn_t, nullptr, FnA, nullptr, NN);
    }

    // final projections (fp32 out)
    mfma_gemm<1, false, false, false, true><<<nodeBlocks, 256, 0, stream>>>(
        FnA, nullptr, Wno_t, nullptr, out, nullptr, NN);
    mfma_gemm<1, false, false, false, true><<<edgeBlocks, 256, 0, stream>>>(
        FeA, nullptr, Weo_t, nullptr, out + (size_t)NN * 128, nullptr, NE);
}

// Round 6
// 725.385 us; speedup vs baseline: 4.9753x; 1.0510x over previous
//
#include <hip/hip_runtime.h>

#define NN 50000
#define NE 250000

typedef __bf16 bf16_8 __attribute__((ext_vector_type(8)));
typedef __bf16 bf16_2 __attribute__((ext_vector_type(2)));
typedef float  f32x4  __attribute__((ext_vector_type(4)));

// XOR-swizzle: 256B rows of bf16[128]; spreads the 16B column slots of
// 8-row stripes across banks (G4) — applied on BOTH ds_write and ds_read.
__device__ __forceinline__ int swz(int row, int bc) {
    return row * 256 + (bc ^ ((row & 7) << 4));
}

// ---------------------------------------------------------------------------
// Weight prep: Wt[c][K] = bf16(W[k][c]) — run once per launch, tiny.
// ---------------------------------------------------------------------------
__global__ __launch_bounds__(256) void wprep(const float* __restrict__ W,
                                             __bf16* __restrict__ Wt, int K) {
    int idx = blockIdx.x * 256 + threadIdx.x;  // over 128*K
    if (idx >= 128 * K) return;
    int c = idx / K, k = idx % K;
    Wt[idx] = (__bf16)W[(size_t)k * 128 + c];
}

// ---------------------------------------------------------------------------
// CSR build (edges are constant across steps -> once per launch).
// ---------------------------------------------------------------------------
__global__ __launch_bounds__(256) void csr_count(const int* __restrict__ edges,
                                                 unsigned* __restrict__ counts) {
    int e = blockIdx.x * 256 + threadIdx.x;
    if (e < NE) atomicAdd(&counts[edges[2 * e + 1]], 1u);
}

// single-block chunked exclusive scan of counts[NN] -> offs[NN+1]
__global__ __launch_bounds__(256) void csr_scan(const unsigned* __restrict__ counts,
                                                unsigned* __restrict__ offs) {
    __shared__ unsigned partial[257];
    const int t = threadIdx.x;
    const int chunk = (NN + 255) / 256;
    const int lo = t * chunk;
    const int hi = (lo + chunk < NN) ? lo + chunk : NN;
    unsigned s = 0;
    for (int i = lo; i < hi; ++i) s += counts[i];
    partial[t + 1] = s;
    if (t == 0) partial[0] = 0;
    __syncthreads();
    if (t == 0)
        for (int i = 1; i <= 256; ++i) partial[i] += partial[i - 1];
    __syncthreads();
    unsigned run = partial[t];
    for (int i = lo; i < hi; ++i) { offs[i] = run; run += counts[i]; }
    if (t == 255) offs[NN] = run;
}

__global__ __launch_bounds__(256) void csr_fill(const int* __restrict__ edges,
                                                unsigned* __restrict__ cursor,
                                                int* __restrict__ csr) {
    int e = blockIdx.x * 256 + threadIdx.x;
    if (e >= NE) return;
    int d = edges[2 * e + 1];
    unsigned p = atomicAdd(&cursor[d], 1u);
    csr[p] = e;
}

// ---------------------------------------------------------------------------
// Dual-job MFMA GEMM: grid = blocksA + blocksB; block picks job by range.
// out[M][128] = concat_h(A0[,A1])[M][KH*128] @ Wt^T, optional relu, optional
// fused score sout[r] = out[r].wsc. If APPLY && apply: the A0 half is the
// 2-way-softmax edge blend a0*FnN[src] + a1*FnN[dst] computed during staging
// (replaces the former edge_apply kernel; same bf16 rounding point).
// 256 thr = 4 waves in 2x2; wave = 64x64 via 4x4 mfma_16x16x32_bf16.
// Fragment maps (m89): A row=lane&15,k=(lane>>4)*8+j; B col=lane&15;
// D col=lane&15,row=(lane>>4)*4+r.
// ---------------------------------------------------------------------------
template<int KH, bool A0F32, bool APPLY, bool RELU, bool SCORE, bool OUTF32>
__global__ __launch_bounds__(256, 2) void mfma_gemm_dual(
    const void* __restrict__ A0a, const void* __restrict__ A1a,
    const __bf16* __restrict__ Wta, const float* __restrict__ wsca,
    void* __restrict__ outa, float* __restrict__ souta, int Ma,
    int blocksA, int applyA,
    const void* __restrict__ A0b, const void* __restrict__ A1b,
    const __bf16* __restrict__ Wtb, const float* __restrict__ wscb,
    void* __restrict__ outb, float* __restrict__ soutb, int Mb, int applyB,
    const int* __restrict__ edges, const float* __restrict__ sn,
    const __bf16* __restrict__ FnN)
{
    __shared__ __align__(16) char smem[65536];
    __shared__ float sred[128];
    char* As = smem;           // 128 rows x 256B (bf16 K=128)
    char* Ws = smem + 32768;   // 128 cols x 256B

    // ---- job select (block-uniform) ----
    const int b = blockIdx.x;
    const bool isA = (b < blocksA);
    const void* A0 = isA ? A0a : A0b;
    const void* A1 = isA ? A1a : A1b;
    const __bf16* Wt = isA ? Wta : Wtb;
    const float* wsc = isA ? wsca : wscb;
    void* out  = isA ? outa : outb;
    float* sout = isA ? souta : soutb;
    const int M = isA ? Ma : Mb;
    const int apply = isA ? applyA : applyB;
    const int rowbase = (isA ? b : b - blocksA) * 128;

    const int t = threadIdx.x;
    const int wv = t >> 6, lane = t & 63;
    const int wr = (wv >> 1) * 64, wc = (wv & 1) * 64;
    const int lr = lane & 15, kq = lane >> 4;

    if (SCORE && t < 128) sred[t] = 0.0f;

    f32x4 acc[4][4] = {};

#pragma unroll
    for (int h = 0; h < KH; ++h) {
        if (h) __syncthreads();  // drain reads before LDS overwrite
        const char* Asrc = (h == 0) ? (const char*)A0 : (const char*)A1;
        const bool srcF32 = (h == 0) && A0F32;
        const bool doApply = APPLY && (h == 0) && (apply != 0);
#pragma unroll
        for (int i = 0; i < 8; ++i) {
            int flat = (i * 256 + t) * 8;
            int row = flat >> 7, k = flat & 127;
            int grow = rowbase + row; if (grow > M - 1) grow = M - 1;
            bf16_8 v;
            if (APPLY && doApply) {
                // fused applied_e: 2-way softmax blend of FnN[src], FnN[dst]
                int src = edges[2 * grow], dst = edges[2 * grow + 1];
                float ss = sn[src], sd = sn[dst];
                float mx = fmaxf(ss, sd);
                float p0 = expf(ss - mx), p1 = expf(sd - mx);
                float inv = 1.0f / (p0 + p1);
                float a0 = p0 * inv, a1 = p1 * inv;
                bf16_8 fs = *(const bf16_8*)(FnN + (size_t)src * 128 + k);
                bf16_8 fd = *(const bf16_8*)(FnN + (size_t)dst * 128 + k);
#pragma unroll
                for (int j = 0; j < 8; ++j)
                    v[j] = (__bf16)(a0 * (float)fs[j] + a1 * (float)fd[j]);
            } else if (srcF32) {
                const float* p = (const float*)Asrc + (size_t)grow * 128 + k;
                float4 u0 = *(const float4*)p, u1 = *(const float4*)(p + 4);
                v[0] = (__bf16)u0.x; v[1] = (__bf16)u0.y;
                v[2] = (__bf16)u0.z; v[3] = (__bf16)u0.w;
                v[4] = (__bf16)u1.x; v[5] = (__bf16)u1.y;
                v[6] = (__bf16)u1.z; v[7] = (__bf16)u1.w;
            } else {
                v = *(const bf16_8*)((const __bf16*)Asrc + (size_t)grow * 128 + k);
            }
            *(bf16_8*)(As + swz(row, k * 2)) = v;
        }
#pragma unroll
        for (int i = 0; i < 8; ++i) {
            int flat = (i * 256 + t) * 8;
            int c = flat >> 7, k = flat & 127;
            bf16_8 v = *(const bf16_8*)(Wt + (size_t)c * (KH * 128) + h * 128 + k);
            *(bf16_8*)(Ws + swz(c, k * 2)) = v;
        }
        __syncthreads();
#pragma unroll
        for (int ks = 0; ks < 4; ++ks) {
            const int bc = ks * 64 + kq * 16;
            bf16_8 a[4], bb[4];
#pragma unroll
            for (int ra = 0; ra < 4; ++ra)
                a[ra] = *(const bf16_8*)(As + swz(wr + 16 * ra + lr, bc));
#pragma unroll
            for (int cb = 0; cb < 4; ++cb)
                bb[cb] = *(const bf16_8*)(Ws + swz(wc + 16 * cb + lr, bc));
#pragma unroll
            for (int ra = 0; ra < 4; ++ra)
#pragma unroll
                for (int cb = 0; cb < 4; ++cb)
                    acc[ra][cb] = __builtin_amdgcn_mfma_f32_16x16x32_bf16(
                        a[ra], bb[cb], acc[ra][cb], 0, 0, 0);
        }
    }

#pragma unroll
    for (int ra = 0; ra < 4; ++ra)
#pragma unroll
        for (int cb = 0; cb < 4; ++cb) {
            const int col = wc + 16 * cb + lr;
#pragma unroll
            for (int r = 0; r < 4; ++r) {
                const int row = rowbase + wr + 16 * ra + kq * 4 + r;
                float v = acc[ra][cb][r];
                if (RELU) v = fmaxf(v, 0.0f);
                if (row < M) {
                    if (OUTF32) ((float*)out)[(size_t)row * 128 + col] = v;
                    else ((__bf16*)out)[(size_t)row * 128 + col] = (__bf16)v;
                }
            }
        }
    if (SCORE) {
        float wsv[4];
#pragma unroll
        for (int cb = 0; cb < 4; ++cb) wsv[cb] = wsc[wc + 16 * cb + lr];
#pragma unroll
        for (int ra = 0; ra < 4; ++ra)
#pragma unroll
            for (int r = 0; r < 4; ++r) {
                float part = acc[ra][0][r] * wsv[0] + acc[ra][1][r] * wsv[1]
                           + acc[ra][2][r] * wsv[2] + acc[ra][3][r] * wsv[3];
                part += __shfl_xor(part, 1); part += __shfl_xor(part, 2);
                part += __shfl_xor(part, 4); part += __shfl_xor(part, 8);
                if (lr == 0)
                    atomicAdd(&sred[wr + 16 * ra + kq * 4 + r], part);
            }
        __syncthreads();
        if (t < 128 && rowbase + t < M) sout[rowbase + t] = sred[t];
    }
}

// ---------------------------------------------------------------------------
// CSR aggregate: one wave per dst node. Pass 1: m = max over incident edges
// of max(s_src, s_e). Pass 2: num += e_n*F_src + e_e*F_e_new, den += e_n+e_e;
// write applied_n = num/den as bf16. No scatter atomics.
// ---------------------------------------------------------------------------
__global__ __launch_bounds__(256) void aggregate_kernel(
    const int* __restrict__ edges, const int* __restrict__ csr,
    const unsigned* __restrict__ offs, const __bf16* __restrict__ FnN,
    const float* __restrict__ s_n, const float* __restrict__ s_e,
    const __bf16* __restrict__ FeN, __bf16* __restrict__ applied_n)
{
    const int t = threadIdx.x;
    const int lane = t & 63;
    const int n = blockIdx.x * 4 + (t >> 6);
    if (n >= NN) return;
    const unsigned beg = offs[n], end = offs[n + 1];

    // pass 1: segment max
    float m = -1e30f;
    for (unsigned i = beg + lane; i < end; i += 64) {
        int e = csr[i];
        int src = edges[2 * e];
        m = fmaxf(m, fmaxf(s_n[src], s_e[e]));
    }
#pragma unroll
    for (int msk = 32; msk >= 1; msk >>= 1) m = fmaxf(m, __shfl_xor(m, msk));

    // pass 2: cooperative row gathers, register accumulation
    float a0 = 0.f, a1 = 0.f, dn = 0.f;
    for (unsigned i = beg; i < end; ++i) {
        int e = csr[i];
        int src = edges[2 * e];
        float en = expf(s_n[src] - m), ee = expf(s_e[e] - m);
        bf16_2 fs = *(const bf16_2*)(FnN + (size_t)src * 128 + lane * 2);
        bf16_2 fe = *(const bf16_2*)(FeN + (size_t)e * 128 + lane * 2);
        a0 += en * (float)fs[0] + ee * (float)fe[0];
        a1 += en * (float)fs[1] + ee * (float)fe[1];
        dn += en + ee;
    }
    const float inv = 1.0f / dn;
    bf16_2 o;
    o[0] = (__bf16)(a0 * inv);
    o[1] = (__bf16)(a1 * inv);
    *(bf16_2*)(applied_n + (size_t)n * 128 + lane * 2) = o;
}

// ---------------------------------------------------------------------------
extern "C" void kernel_launch(void* const* d_in, const int* in_sizes, int n_in,
                              void* d_out, int out_size, void* d_ws, size_t ws_size,
                              hipStream_t stream)
{
    const float* obj         = (const float*)d_in[0];
    const float* pred        = (const float*)d_in[1];
    const int*   edges       = (const int*)d_in[2];
    const float* W_node      = (const float*)d_in[3];
    const float* W_obj_score = (const float*)d_in[4];
    const float* W_edge      = (const float*)d_in[5];
    const float* W_rel_score = (const float*)d_in[6];
    const float* W_phi_node  = (const float*)d_in[7];
    const float* W_phi_edge  = (const float*)d_in[8];
    const float* W_node_out  = (const float*)d_in[9];
    const float* W_edge_out  = (const float*)d_in[10];
    float* out = (float*)d_out;

    char*  ws  = (char*)d_ws;
    size_t off = 0;
    auto alloc = [&](size_t nbytes) -> void* {
        void* p = ws + off;
        off = (off + nbytes + 255) & ~(size_t)255;
        return p;
    };
    __bf16*   FnA   = (__bf16*)alloc((size_t)NN * 128 * 2);   // F_n state
    __bf16*   FnN   = (__bf16*)alloc((size_t)NN * 128 * 2);   // F_n @ W_node
    __bf16*   FnApp = (__bf16*)alloc((size_t)NN * 128 * 2);   // applied_n
    float*    s_n   = (float*)alloc((size_t)NN * 4);
    __bf16*   FeA   = (__bf16*)alloc((size_t)NE * 128 * 2);   // F_e state
    __bf16*   FeN   = (__bf16*)alloc((size_t)NE * 128 * 2);   // F_e @ W_edge
    float*    s_e   = (float*)alloc((size_t)NE * 4);
    unsigned* counts = (unsigned*)alloc((size_t)NN * 4);
    unsigned* offs   = (unsigned*)alloc((size_t)(NN + 1) * 4);
    unsigned* cursor = (unsigned*)alloc((size_t)NN * 4);
    int*      csr    = (int*)alloc((size_t)NE * 4);
    __bf16*   Wn_t  = (__bf16*)alloc((size_t)128 * 128 * 2);
    __bf16*   We_t  = (__bf16*)alloc((size_t)128 * 128 * 2);
    __bf16*   Wpn_t = (__bf16*)alloc((size_t)128 * 256 * 2);
    __bf16*   Wpe_t = (__bf16*)alloc((size_t)128 * 256 * 2);
    __bf16*   Wno_t = (__bf16*)alloc((size_t)128 * 128 * 2);
    __bf16*   Weo_t = (__bf16*)alloc((size_t)128 * 128 * 2);
    (void)ws_size; (void)in_sizes; (void)n_in; (void)out_size;

    // weight prep (tiny)
    wprep<<<64, 256, 0, stream>>>(W_node, Wn_t, 128);
    wprep<<<64, 256, 0, stream>>>(W_edge, We_t, 128);
    wprep<<<128, 256, 0, stream>>>(W_phi_node, Wpn_t, 256);
    wprep<<<128, 256, 0, stream>>>(W_phi_edge, Wpe_t, 256);
    wprep<<<64, 256, 0, stream>>>(W_node_out, Wno_t, 128);
    wprep<<<64, 256, 0, stream>>>(W_edge_out, Weo_t, 128);

    // CSR build (once per launch; edges constant across steps)
    const int eB = (NE + 255) / 256;
    hipMemsetAsync(counts, 0, (size_t)NN * 4, stream);
    csr_count<<<eB, 256, 0, stream>>>(edges, counts);
    csr_scan<<<1, 256, 0, stream>>>(counts, offs);
    hipMemcpyAsync(cursor, offs, (size_t)NN * 4, hipMemcpyDeviceToDevice, stream);
    csr_fill<<<eB, 256, 0, stream>>>(edges, cursor, csr);

    const int nodeBlocks = (NN + 127) / 128;   // 391
    const int edgeBlocks = (NE + 127) / 128;   // 1954
    const int dualBlocks = nodeBlocks + edgeBlocks;
    const int aggBlocks  = (NN + 3) / 4;       // 12500

    for (int step = 0; step < 2; ++step) {
        // dual GEMM: node {F_n@W_node, s_n} + edge {F_e@W_edge, s_e}
        if (step == 0)
            mfma_gemm_dual<1, true, false, false, true, false><<<dualBlocks, 256, 0, stream>>>(
                obj,  nullptr, Wn_t, W_obj_score, FnN, s_n, NN, nodeBlocks, 0,
                pred, nullptr, We_t, W_rel_score, FeN, s_e, NE, 0,
                nullptr, nullptr, nullptr);
        else
            mfma_gemm_dual<1, false, false, false, true, false><<<dualBlocks, 256, 0, stream>>>(
                FnA, nullptr, Wn_t, W_obj_score, FnN, s_n, NN, nodeBlocks, 0,
                FeA, nullptr, We_t, W_rel_score, FeN, s_e, NE, 0,
                nullptr, nullptr, nullptr);
        // CSR aggregate -> applied_n (bf16)
        aggregate_kernel<<<aggBlocks, 256, 0, stream>>>(
            edges, csr, offs, FnN, s_n, s_e, FeN, FnApp);
        // dual phi: edge {relu(concat(applied_e(fused), FeN) @ W_phi_edge)}
        //         + node {relu(concat(applied_n, FnN) @ W_phi_node)}
        mfma_gemm_dual<2, false, true, true, false, false><<<dualBlocks, 256, 0, stream>>>(
            nullptr, FeN, Wpe_t, nullptr, FeA, nullptr, NE, edgeBlocks, 1,
            FnApp,   FnN, Wpn_t, nullptr, FnA, nullptr, NN, 0,
            edges, s_n, FnN);
    }

    // final projections (fp32 out), dual
    mfma_gemm_dual<1, false, false, false, false, true><<<dualBlocks, 256, 0, stream>>>(
        FnA, nullptr, Wno_t, nullptr, out, nullptr, NN, nodeBlocks, 0,
        FeA, nullptr, Weo_t, nullptr, out + (size_t)NN * 128, nullptr, NE, 0,
        nullptr, nullptr, nullptr);
}